// Round 1
// baseline (42385.037 us; speedup 1.0000x reference)
//
#include <hip/hip_runtime.h>
#include <math.h>

// Decoder: 500 sequential steps of (attention -> LSTM0 -> LSTM1 -> logits/argmax).
// All fp32 (recurrence + argmax feedback are precision-critical; no fp32 MFMA on CDNA4
// so GEMMs run on the vector ALU).
//
// Per step: attn_kernel (dim3(8,64)) -> lstm0_kernel (dim3(64,8)) -> lstm1_kernel (dim3(64,8)).
// attn_kernel also emits log_softmax(prev logits) + argmax (idx) for the CURRENT step's input.
// Split-k attention partials combined by last-arriving block (threadfence + agent-scope atomic).

#define NB 64      // batch
#define NS 500     // src len
#define NH 512     // hidden
#define NT 500     // tgt len
#define NCH 8      // attention chunks per batch row
#define CHS 63     // src positions per chunk (8*63 >= 500)

// ---------------------------------------------------------------- init
__global__ __launch_bounds__(256) void init_kernel(
    const float* __restrict__ h1_0, const float* __restrict__ c1_0,
    const float* __restrict__ h2_0, const float* __restrict__ c2_0,
    const int* __restrict__ tgt,
    float* __restrict__ h1a, float* __restrict__ c1,
    float* __restrict__ h2a, float* __restrict__ c2,
    int* __restrict__ idx, int* __restrict__ cnt)
{
    int gid = blockIdx.x * 256 + threadIdx.x;   // grid 128 -> 32768 = 64*512
    h1a[gid] = h1_0[gid];
    c1[gid]  = c1_0[gid];
    h2a[gid] = h2_0[gid];
    c2[gid]  = c2_0[gid];
    if (gid < NB) { idx[gid] = tgt[gid * NT]; cnt[gid] = 0; }
}

// ------------------------------------------------- E = emb @ W_ih0[:, :512].T + b_ih0 + b_hh0
__global__ __launch_bounds__(256) void eproj_kernel(
    const float* __restrict__ emb, const float* __restrict__ Wih0,
    const float* __restrict__ bih0, const float* __restrict__ bhh0,
    float* __restrict__ E)
{
    int gid = blockIdx.x * 256 + threadIdx.x;   // grid 24 -> 6144 = 3*2048
    int v = gid >> 11, g = gid & 2047;
    const float4* wr = (const float4*)(Wih0 + (size_t)g * 1536);
    const float4* er = (const float4*)(emb + v * 512);
    float s = bih0[g] + bhh0[g];
    #pragma unroll 4
    for (int i = 0; i < 128; ++i) {
        float4 w = wr[i], e = er[i];
        s += w.x*e.x + w.y*e.y + w.z*e.z + w.w*e.w;
    }
    E[v * 2048 + g] = s;
}

// ---------------------------------------------------------------- attention (+ prev logits)
// grid (8 chunks, 64 b), 256 threads. Per-wave online softmax over its src rows; ctx read ONCE.
__global__ __launch_bounds__(256) void attn_kernel(
    const float* __restrict__ ctx,   // [64,500,1024]
    const float* __restrict__ h2_in, // [64,512]
    const float* __restrict__ Wl, const float* __restrict__ bl,
    float* __restrict__ pm, float* __restrict__ pl, float* __restrict__ pacc,
    float* __restrict__ align_g, int* __restrict__ cnt, int* __restrict__ idx,
    float* __restrict__ out, int t)
{
    __shared__ alignas(16) float q_s[512];
    __shared__ alignas(16) float wacc[4 * 1024];
    __shared__ float wm[4], wl_s[4];
    __shared__ float lg[3];
    __shared__ int is_last;
    const int tid = threadIdx.x;
    const int ch = blockIdx.x, b = blockIdx.y;

    q_s[tid]       = h2_in[b * 512 + tid];
    q_s[tid + 256] = h2_in[b * 512 + 256 + tid];
    __syncthreads();

    // logits/argmax for step t-1 (input feedback for this step); block-uniform condition.
    if (ch == 0 && t > 0) {
        if (tid < 192) {
            int v = tid >> 6, lane = tid & 63;
            float p = 0.f;
            #pragma unroll
            for (int j = 0; j < 8; ++j)
                p += q_s[lane * 8 + j] * Wl[v * 512 + lane * 8 + j];
            for (int off = 32; off; off >>= 1) p += __shfl_xor(p, off);
            if (lane == 0) lg[v] = p + bl[v];
        }
        __syncthreads();
        if (tid == 0) {
            float m = fmaxf(lg[0], fmaxf(lg[1], lg[2]));
            float e0 = expf(lg[0] - m), e1 = expf(lg[1] - m), e2 = expf(lg[2] - m);
            float ls = logf(e0 + e1 + e2);
            float* o = out + ((size_t)b * NT + (t - 1)) * 3;
            o[0] = lg[0] - m - ls; o[1] = lg[1] - m - ls; o[2] = lg[2] - m - ls;
            int am = 0;                       // first-max tie-break, matches jnp.argmax
            if (lg[1] > lg[am]) am = 1;
            if (lg[2] > lg[am]) am = 2;
            idx[b] = am;
        }
    }

    const int lane = tid & 63, wave = tid >> 6;
    const int s0 = ch * CHS;
    const int s1 = (s0 + CHS < NS) ? s0 + CHS : NS;
    float4 q0 = ((const float4*)q_s)[lane];        // d = 4*lane .. +3   (0..255)
    float4 q1 = ((const float4*)q_s)[64 + lane];   // 256..511
    float m = -INFINITY, l = 0.f;
    float4 a0 = {0,0,0,0}, a1 = {0,0,0,0}, a2 = {0,0,0,0}, a3 = {0,0,0,0};

    for (int s = s0 + wave; s < s1; s += 4) {
        const float4* crow = (const float4*)(ctx + ((size_t)b * NS + s) * 1024);
        float4 v0 = crow[lane], v1 = crow[64 + lane], v2 = crow[128 + lane], v3 = crow[192 + lane];
        // q = cat(h2,h2): d>=512 wraps to q0/q1
        float p = v0.x*q0.x + v0.y*q0.y + v0.z*q0.z + v0.w*q0.w
                + v1.x*q1.x + v1.y*q1.y + v1.z*q1.z + v1.w*q1.w
                + v2.x*q0.x + v2.y*q0.y + v2.z*q0.z + v2.w*q0.w
                + v3.x*q1.x + v3.y*q1.y + v3.z*q1.z + v3.w*q1.w;
        for (int off = 32; off; off >>= 1) p += __shfl_xor(p, off);
        float mn = fmaxf(m, p);
        float al = expf(m - mn);   // first iter: expf(-inf) = 0
        float w  = expf(p - mn);
        l = l * al + w;
        a0.x = a0.x*al + w*v0.x; a0.y = a0.y*al + w*v0.y; a0.z = a0.z*al + w*v0.z; a0.w = a0.w*al + w*v0.w;
        a1.x = a1.x*al + w*v1.x; a1.y = a1.y*al + w*v1.y; a1.z = a1.z*al + w*v1.z; a1.w = a1.w*al + w*v1.w;
        a2.x = a2.x*al + w*v2.x; a2.y = a2.y*al + w*v2.y; a2.z = a2.z*al + w*v2.z; a2.w = a2.w*al + w*v2.w;
        a3.x = a3.x*al + w*v3.x; a3.y = a3.y*al + w*v3.y; a3.z = a3.z*al + w*v3.z; a3.w = a3.w*al + w*v3.w;
        m = mn;
    }
    ((float4*)wacc)[wave * 256 + lane]       = a0;
    ((float4*)wacc)[wave * 256 + 64 + lane]  = a1;
    ((float4*)wacc)[wave * 256 + 128 + lane] = a2;
    ((float4*)wacc)[wave * 256 + 192 + lane] = a3;
    if (lane == 0) { wm[wave] = m; wl_s[wave] = l; }
    __syncthreads();
    {   // combine 4 wave-partials -> chunk partial
        float M = fmaxf(fmaxf(wm[0], wm[1]), fmaxf(wm[2], wm[3]));
        float e0 = expf(wm[0]-M), e1 = expf(wm[1]-M), e2 = expf(wm[2]-M), e3 = expf(wm[3]-M);
        float L = e0*wl_s[0] + e1*wl_s[1] + e2*wl_s[2] + e3*wl_s[3];
        const float4* w4 = (const float4*)wacc;
        float4 x0 = w4[tid], x1 = w4[256 + tid], x2 = w4[512 + tid], x3 = w4[768 + tid];
        float4 r;
        r.x = e0*x0.x + e1*x1.x + e2*x2.x + e3*x3.x;
        r.y = e0*x0.y + e1*x1.y + e2*x2.y + e3*x3.y;
        r.z = e0*x0.z + e1*x1.z + e2*x2.z + e3*x3.z;
        r.w = e0*x0.w + e1*x1.w + e2*x2.w + e3*x3.w;
        ((float4*)pacc)[(b * NCH + ch) * 256 + tid] = r;
        if (tid == 0) { pm[b * NCH + ch] = M; pl[b * NCH + ch] = L; }
    }
    __syncthreads();                 // drains vmcnt: partial stores are in L2
    if (tid == 0) {
        __threadfence();             // device-scope writeback (cross-XCD visibility)
        int old = __hip_atomic_fetch_add(cnt + b, 1, __ATOMIC_ACQ_REL, __HIP_MEMORY_SCOPE_AGENT);
        is_last = (old == NCH * t + (NCH - 1)) ? 1 : 0;   // monotone counter: no reset needed
    }
    __syncthreads();
    if (is_last) {                   // last block for this b combines all 8 chunks -> align
        float M = -INFINITY;
        #pragma unroll
        for (int k = 0; k < NCH; ++k) M = fmaxf(M, pm[b * NCH + k]);
        float e[NCH]; float L = 0.f;
        #pragma unroll
        for (int k = 0; k < NCH; ++k) { e[k] = expf(pm[b * NCH + k] - M); L += e[k] * pl[b * NCH + k]; }
        float invL = 1.f / L;
        const float4* p4 = (const float4*)pacc;
        float4 r = {0,0,0,0};
        #pragma unroll
        for (int k = 0; k < NCH; ++k) {
            float4 x = p4[(b * NCH + k) * 256 + tid];
            r.x += e[k]*x.x; r.y += e[k]*x.y; r.z += e[k]*x.z; r.w += e[k]*x.w;
        }
        r.x *= invL; r.y *= invL; r.z *= invL; r.w *= invL;
        ((float4*)align_g)[b * 256 + tid] = r;
    }
}

// ---------------------------------------------------------------- LSTM cell 0
// grid (64 j-chunks, 8 b-groups of 8). 256 thr = 16 k-slices x 16 row-pairs.
// LDS act[d][b] stride 10 floats (conflict-free float2 reads, 61.4 KB).
__global__ __launch_bounds__(256) void lstm0_kernel(
    const float* __restrict__ align_g, const float* __restrict__ h1_in,
    float* __restrict__ c1, const float* __restrict__ E,
    const int* __restrict__ idx, const float* __restrict__ Wih0,
    const float* __restrict__ Whh0, float* __restrict__ h1_out)
{
    __shared__ alignas(16) float smem[1536 * 10];
    __shared__ int idx_s[8];
    const int tid = threadIdx.x;
    const int jc = blockIdx.x;          // 0..63 -> 8 j's
    const int b0 = blockIdx.y << 3;     // 8 b per block
    {   // stage align (d<1024) + h1 (d 1024..1535) into LDS [d][b]
        const int dc = tid & 31, bb = tid >> 5;
        const float* arow = align_g + (size_t)(b0 + bb) * 1024;
        const float* hrow = h1_in + (size_t)(b0 + bb) * 512;
        #pragma unroll 4
        for (int i = 0; i < 32; ++i) { int d = dc + (i << 5); smem[d * 10 + bb] = arow[d]; }
        #pragma unroll 4
        for (int i = 0; i < 16; ++i) { int d = dc + (i << 5); smem[(1024 + d) * 10 + bb] = hrow[d]; }
        if (tid < 8) idx_s[tid] = idx[b0 + tid];
    }
    __syncthreads();
    const int lane = tid & 63, wave = tid >> 6;
    const int sl = lane & 15;                    // k-slice 0..15
    const int rt = (wave << 2) | (lane >> 4);    // row-pair 0..15  (rows rt, rt+16)
    const int g0r = ((rt      ) >> 3) * 512 + (jc << 3) + (rt & 7);
    const int g1r = ((rt + 16 ) >> 3) * 512 + (jc << 3) + (rt & 7);
    const float* wa0 = Wih0 + (size_t)g0r * 1536 + 512;
    const float* wa1 = Wih0 + (size_t)g1r * 1536 + 512;
    const float* wh0 = Whh0 + (size_t)g0r * 512;
    const float* wh1 = Whh0 + (size_t)g1r * 512;
    float acc[2][8];
    #pragma unroll
    for (int r = 0; r < 2; ++r)
        #pragma unroll
        for (int q = 0; q < 8; ++q) acc[r][q] = 0.f;

    #pragma unroll 2
    for (int i = 0; i < 64; ++i) {               // align part: d = sl + 16i < 1024
        int d = sl + (i << 4);
        float w0 = wa0[d], w1 = wa1[d];
        const float2* a2 = (const float2*)(smem + d * 10);
        float2 x0 = a2[0], x1 = a2[1], x2 = a2[2], x3 = a2[3];
        acc[0][0] = fmaf(w0, x0.x, acc[0][0]); acc[1][0] = fmaf(w1, x0.x, acc[1][0]);
        acc[0][1] = fmaf(w0, x0.y, acc[0][1]); acc[1][1] = fmaf(w1, x0.y, acc[1][1]);
        acc[0][2] = fmaf(w0, x1.x, acc[0][2]); acc[1][2] = fmaf(w1, x1.x, acc[1][2]);
        acc[0][3] = fmaf(w0, x1.y, acc[0][3]); acc[1][3] = fmaf(w1, x1.y, acc[1][3]);
        acc[0][4] = fmaf(w0, x2.x, acc[0][4]); acc[1][4] = fmaf(w1, x2.x, acc[1][4]);
        acc[0][5] = fmaf(w0, x2.y, acc[0][5]); acc[1][5] = fmaf(w1, x2.y, acc[1][5]);
        acc[0][6] = fmaf(w0, x3.x, acc[0][6]); acc[1][6] = fmaf(w1, x3.x, acc[1][6]);
        acc[0][7] = fmaf(w0, x3.y, acc[0][7]); acc[1][7] = fmaf(w1, x3.y, acc[1][7]);
    }
    #pragma unroll 2
    for (int i = 0; i < 32; ++i) {               // h1 part: d = sl + 16i < 512
        int d = sl + (i << 4);
        float w0 = wh0[d], w1 = wh1[d];
        const float2* a2 = (const float2*)(smem + (1024 + d) * 10);
        float2 x0 = a2[0], x1 = a2[1], x2 = a2[2], x3 = a2[3];
        acc[0][0] = fmaf(w0, x0.x, acc[0][0]); acc[1][0] = fmaf(w1, x0.x, acc[1][0]);
        acc[0][1] = fmaf(w0, x0.y, acc[0][1]); acc[1][1] = fmaf(w1, x0.y, acc[1][1]);
        acc[0][2] = fmaf(w0, x1.x, acc[0][2]); acc[1][2] = fmaf(w1, x1.x, acc[1][2]);
        acc[0][3] = fmaf(w0, x1.y, acc[0][3]); acc[1][3] = fmaf(w1, x1.y, acc[1][3]);
        acc[0][4] = fmaf(w0, x2.x, acc[0][4]); acc[1][4] = fmaf(w1, x2.x, acc[1][4]);
        acc[0][5] = fmaf(w0, x2.y, acc[0][5]); acc[1][5] = fmaf(w1, x2.y, acc[1][5]);
        acc[0][6] = fmaf(w0, x3.x, acc[0][6]); acc[1][6] = fmaf(w1, x3.x, acc[1][6]);
        acc[0][7] = fmaf(w0, x3.y, acc[0][7]); acc[1][7] = fmaf(w1, x3.y, acc[1][7]);
    }
    // reduce over 16 k-slices (lane bits 0..3)
    float* af = &acc[0][0];
    #pragma unroll
    for (int mk = 1; mk <= 8; mk <<= 1)
        #pragma unroll
        for (int k = 0; k < 16; ++k) af[k] += __shfl_xor(af[k], mk);
    __syncthreads();                 // act no longer needed; alias gred into smem
    float* gred = smem;
    if (sl == 0) {
        #pragma unroll
        for (int q = 0; q < 8; ++q) {
            gred[(rt     ) * 8 + q] = acc[0][q];
            gred[(rt + 16) * 8 + q] = acc[1][q];
        }
    }
    __syncthreads();
    if (tid < 64) {                  // pointwise: 8 j x 8 b
        int j2 = tid >> 3, bb = tid & 7;
        int jg = (jc << 3) + j2, bg = b0 + bb;
        float gv[4];
        #pragma unroll
        for (int g = 0; g < 4; ++g)
            gv[g] = gred[(g * 8 + j2) * 8 + bb] + E[idx_s[bb] * 2048 + g * 512 + jg];
        float ig = 1.f / (1.f + expf(-gv[0]));
        float fg = 1.f / (1.f + expf(-gv[1]));
        float gg = tanhf(gv[2]);
        float og = 1.f / (1.f + expf(-gv[3]));
        float cn = fg * c1[bg * 512 + jg] + ig * gg;
        c1[bg * 512 + jg] = cn;
        h1_out[bg * 512 + jg] = og * tanhf(cn);
    }
}

// ---------------------------------------------------------------- LSTM cell 1 (+ c2/h2 update)
__global__ __launch_bounds__(256) void lstm1_kernel(
    const float* __restrict__ h1n, const float* __restrict__ h2_in,
    float* __restrict__ c2, const float* __restrict__ Wih1,
    const float* __restrict__ Whh1, const float* __restrict__ bih1,
    const float* __restrict__ bhh1, float* __restrict__ h2_out)
{
    __shared__ alignas(16) float smem[1024 * 10];
    const int tid = threadIdx.x;
    const int jc = blockIdx.x;
    const int b0 = blockIdx.y << 3;
    {
        const int dc = tid & 31, bb = tid >> 5;
        const float* xrow = h1n  + (size_t)(b0 + bb) * 512;
        const float* hrow = h2_in + (size_t)(b0 + bb) * 512;
        #pragma unroll 4
        for (int i = 0; i < 16; ++i) { int d = dc + (i << 5); smem[d * 10 + bb] = xrow[d]; }
        #pragma unroll 4
        for (int i = 0; i < 16; ++i) { int d = dc + (i << 5); smem[(512 + d) * 10 + bb] = hrow[d]; }
    }
    __syncthreads();
    const int lane = tid & 63, wave = tid >> 6;
    const int sl = lane & 15;
    const int rt = (wave << 2) | (lane >> 4);
    const int g0r = ((rt      ) >> 3) * 512 + (jc << 3) + (rt & 7);
    const int g1r = ((rt + 16 ) >> 3) * 512 + (jc << 3) + (rt & 7);
    const float* wi0 = Wih1 + (size_t)g0r * 512;
    const float* wi1 = Wih1 + (size_t)g1r * 512;
    const float* wh0 = Whh1 + (size_t)g0r * 512;
    const float* wh1 = Whh1 + (size_t)g1r * 512;
    float acc[2][8];
    #pragma unroll
    for (int r = 0; r < 2; ++r)
        #pragma unroll
        for (int q = 0; q < 8; ++q) acc[r][q] = 0.f;
    #pragma unroll 2
    for (int i = 0; i < 32; ++i) {               // x = h1n
        int d = sl + (i << 4);
        float w0 = wi0[d], w1 = wi1[d];
        const float2* a2 = (const float2*)(smem + d * 10);
        float2 x0 = a2[0], x1 = a2[1], x2 = a2[2], x3 = a2[3];
        acc[0][0] = fmaf(w0, x0.x, acc[0][0]); acc[1][0] = fmaf(w1, x0.x, acc[1][0]);
        acc[0][1] = fmaf(w0, x0.y, acc[0][1]); acc[1][1] = fmaf(w1, x0.y, acc[1][1]);
        acc[0][2] = fmaf(w0, x1.x, acc[0][2]); acc[1][2] = fmaf(w1, x1.x, acc[1][2]);
        acc[0][3] = fmaf(w0, x1.y, acc[0][3]); acc[1][3] = fmaf(w1, x1.y, acc[1][3]);
        acc[0][4] = fmaf(w0, x2.x, acc[0][4]); acc[1][4] = fmaf(w1, x2.x, acc[1][4]);
        acc[0][5] = fmaf(w0, x2.y, acc[0][5]); acc[1][5] = fmaf(w1, x2.y, acc[1][5]);
        acc[0][6] = fmaf(w0, x3.x, acc[0][6]); acc[1][6] = fmaf(w1, x3.x, acc[1][6]);
        acc[0][7] = fmaf(w0, x3.y, acc[0][7]); acc[1][7] = fmaf(w1, x3.y, acc[1][7]);
    }
    #pragma unroll 2
    for (int i = 0; i < 32; ++i) {               // h = h2
        int d = sl + (i << 4);
        float w0 = wh0[d], w1 = wh1[d];
        const float2* a2 = (const float2*)(smem + (512 + d) * 10);
        float2 x0 = a2[0], x1 = a2[1], x2 = a2[2], x3 = a2[3];
        acc[0][0] = fmaf(w0, x0.x, acc[0][0]); acc[1][0] = fmaf(w1, x0.x, acc[1][0]);
        acc[0][1] = fmaf(w0, x0.y, acc[0][1]); acc[1][1] = fmaf(w1, x0.y, acc[1][1]);
        acc[0][2] = fmaf(w0, x1.x, acc[0][2]); acc[1][2] = fmaf(w1, x1.x, acc[1][2]);
        acc[0][3] = fmaf(w0, x1.y, acc[0][3]); acc[1][3] = fmaf(w1, x1.y, acc[1][3]);
        acc[0][4] = fmaf(w0, x2.x, acc[0][4]); acc[1][4] = fmaf(w1, x2.x, acc[1][4]);
        acc[0][5] = fmaf(w0, x2.y, acc[0][5]); acc[1][5] = fmaf(w1, x2.y, acc[1][5]);
        acc[0][6] = fmaf(w0, x3.x, acc[0][6]); acc[1][6] = fmaf(w1, x3.x, acc[1][6]);
        acc[0][7] = fmaf(w0, x3.y, acc[0][7]); acc[1][7] = fmaf(w1, x3.y, acc[1][7]);
    }
    float* af = &acc[0][0];
    #pragma unroll
    for (int mk = 1; mk <= 8; mk <<= 1)
        #pragma unroll
        for (int k = 0; k < 16; ++k) af[k] += __shfl_xor(af[k], mk);
    __syncthreads();
    float* gred = smem;
    if (sl == 0) {
        #pragma unroll
        for (int q = 0; q < 8; ++q) {
            gred[(rt     ) * 8 + q] = acc[0][q];
            gred[(rt + 16) * 8 + q] = acc[1][q];
        }
    }
    __syncthreads();
    if (tid < 64) {
        int j2 = tid >> 3, bb = tid & 7;
        int jg = (jc << 3) + j2, bg = b0 + bb;
        float gv[4];
        #pragma unroll
        for (int g = 0; g < 4; ++g)
            gv[g] = gred[(g * 8 + j2) * 8 + bb] + bih1[g * 512 + jg] + bhh1[g * 512 + jg];
        float ig = 1.f / (1.f + expf(-gv[0]));
        float fg = 1.f / (1.f + expf(-gv[1]));
        float gg = tanhf(gv[2]);
        float og = 1.f / (1.f + expf(-gv[3]));
        float cn = fg * c2[bg * 512 + jg] + ig * gg;
        c2[bg * 512 + jg] = cn;
        h2_out[bg * 512 + jg] = og * tanhf(cn);
    }
}

// ---------------------------------------------------------------- tail: logits t=499 + target copy
__global__ __launch_bounds__(256) void tail_kernel(
    const float* __restrict__ h2f, const float* __restrict__ Wl,
    const float* __restrict__ bl, const int* __restrict__ tgt,
    float* __restrict__ out)
{
    __shared__ float q_s[512];
    __shared__ float lg[3];
    const int b = blockIdx.x, tid = threadIdx.x;
    q_s[tid]       = h2f[b * 512 + tid];
    q_s[tid + 256] = h2f[b * 512 + 256 + tid];
    __syncthreads();
    if (tid < 192) {
        int v = tid >> 6, lane = tid & 63;
        float p = 0.f;
        #pragma unroll
        for (int j = 0; j < 8; ++j)
            p += q_s[lane * 8 + j] * Wl[v * 512 + lane * 8 + j];
        for (int off = 32; off; off >>= 1) p += __shfl_xor(p, off);
        if (lane == 0) lg[v] = p + bl[v];
    }
    __syncthreads();
    if (tid == 0) {
        float m = fmaxf(lg[0], fmaxf(lg[1], lg[2]));
        float e0 = expf(lg[0] - m), e1 = expf(lg[1] - m), e2 = expf(lg[2] - m);
        float ls = logf(e0 + e1 + e2);
        float* o = out + ((size_t)b * NT + (NT - 1)) * 3;
        o[0] = lg[0] - m - ls; o[1] = lg[1] - m - ls; o[2] = lg[2] - m - ls;
    }
    for (int i = tid; i < NT; i += 256)
        out[NB * NT * 3 + b * NT + i] = (float)tgt[b * NT + i];
}

// ---------------------------------------------------------------- launch
extern "C" void kernel_launch(void* const* d_in, const int* in_sizes, int n_in,
                              void* d_out, int out_size, void* d_ws, size_t ws_size,
                              hipStream_t stream)
{
    const float* ctx  = (const float*)d_in[0];
    const int*   tgt  = (const int*)d_in[1];
    // d_in[2] = teacher_ratio (always 0) - unused
    const float* h1_0 = (const float*)d_in[3];
    const float* c1_0 = (const float*)d_in[4];
    const float* h2_0 = (const float*)d_in[5];
    const float* c2_0 = (const float*)d_in[6];
    const float* emb  = (const float*)d_in[7];
    const float* Wih0 = (const float*)d_in[8];
    const float* Whh0 = (const float*)d_in[9];
    const float* bih0 = (const float*)d_in[10];
    const float* bhh0 = (const float*)d_in[11];
    const float* Wih1 = (const float*)d_in[12];
    const float* Whh1 = (const float*)d_in[13];
    const float* bih1 = (const float*)d_in[14];
    const float* bhh1 = (const float*)d_in[15];
    const float* Wl   = (const float*)d_in[16];
    const float* bl   = (const float*)d_in[17];
    float* out = (float*)d_out;

    float* f = (float*)d_ws;
    float* h1a   = f;              float* h1b = f + 32768;
    float* h2a   = f + 65536;      float* h2b = f + 98304;
    float* c1    = f + 131072;     float* c2  = f + 163840;
    float* E     = f + 196608;     // 3*2048
    float* pm    = f + 202752;     // 512
    float* pl    = f + 203264;     // 512
    float* pacc  = f + 203776;     // 512*1024
    float* algn  = f + 728064;     // 64*1024
    int*   idx   = (int*)(f + 793600);   // 64
    int*   cnt   = idx + 64;             // 64

    init_kernel<<<128, 256, 0, stream>>>(h1_0, c1_0, h2_0, c2_0, tgt, h1a, c1, h2a, c2, idx, cnt);
    eproj_kernel<<<24, 256, 0, stream>>>(emb, Wih0, bih0, bhh0, E);

    for (int t = 0; t < NT; ++t) {
        float* h1i = (t & 1) ? h1b : h1a;  float* h1o = (t & 1) ? h1a : h1b;
        float* h2i = (t & 1) ? h2b : h2a;  float* h2o = (t & 1) ? h2a : h2b;
        attn_kernel<<<dim3(NCH, NB), 256, 0, stream>>>(ctx, h2i, Wl, bl, pm, pl, pacc,
                                                       algn, cnt, idx, out, t);
        lstm0_kernel<<<dim3(64, 8), 256, 0, stream>>>(algn, h1i, c1, E, idx, Wih0, Whh0, h1o);
        lstm1_kernel<<<dim3(64, 8), 256, 0, stream>>>(h1o, h2i, c2, Wih1, Whh1, bih1, bhh1, h2o);
    }
    // after t=499, h2 state lives in h2a (500 is even)
    tail_kernel<<<NB, 256, 0, stream>>>(h2a, Wl, bl, tgt, out);
}